// Round 11
// baseline (720.613 us; speedup 1.0000x reference)
//
#include <hip/hip_runtime.h>
#include <hip/hip_bf16.h>

using bf16 = __hip_bfloat16;
using bf16x8 = __attribute__((ext_vector_type(8))) short;
using f32x4 = __attribute__((ext_vector_type(4))) float;

static __device__ __forceinline__ float ldv(bf16 v) { return __bfloat162float(v); }
static __device__ __forceinline__ bf16 f2b(float v) { return __float2bfloat16(v); }

// async global->LDS 16B copy: lds dest = wave-uniform base + lane*16 (HW)
static __device__ __forceinline__ void gload_lds16(const bf16* g, bf16* l) {
  __builtin_amdgcn_global_load_lds(
      (const __attribute__((address_space(1))) unsigned int*)g,
      (__attribute__((address_space(3))) unsigned int*)l, 16, 0, 0);
}

struct WtPart {
  const float* src;
  int N;
  bf16* dst;
  int K;
};

struct GemmDesc {
  const bf16* A; int lda;
  const bf16* A2; int lda2; int K1;
  const bf16* Bt;             // bf16 [N][K] pre-transposed (or null)
  const float* Bf; int ldbf;  // fp32 [K][N] direct source when Bt==null
  void* C; int ldc; int K;
  int nx, cw, ch;
  int ep;    // bit0: sigmoid-gated EMA; bit1: memories side-write (raw)
  int cf32;  // C is float
  int nblk;  // blocks in this segment
  // fused per-head l2norm epilogue, per 1024-col group g = col>>10:
  // nmode[g]: 0 = passthrough, 1 = l2norm (*ns1*ns2*nmul)
  const float* ns1[4];
  const float* ns2[4];
  float nmul[4];
  int nmode[4];
};

struct AttnDesc {
  const bf16* qp; int q_rstride;
  const bf16* kp; int k_rstride;
  const bf16* vtp; int v_nstride;
  const bf16* bshuf;
  int causal, nkeys, qrows_per_blk, kbase0, krows_per_blk, nqt, nzb, nblk;
  bf16* op; int o_rstride, o_coff, o_hstride;
};

// ---------------------------------------------------------------------------
// pre_kernel: fused {LayerNorm rows} + {weight transpose+cvt}.
// B < nln: ln (first nln0 rows = set 0, rest = set 1; raw = bf16(x) side out).
// B >= nln: wtrans, flattened 1D: kx = L % nkx, y = L / nkx (y ranges pick part).
// ---------------------------------------------------------------------------
__global__ __launch_bounds__(256) void pre_kernel(
    int nln0, int nln,
    const float* x0, const float* g0, const float* a0, bf16* o0, bf16* r0,
    const float* x1, const float* g1, const float* a1, bf16* o1, bf16* r1,
    int nkx, WtPart pa, int ya, WtPart pb, int yb, WtPart pc, int yc, WtPart pd) {
  __shared__ bf16 tile[64][72];
  __shared__ float red[8];
  const int t = threadIdx.x;
  const int B = blockIdx.x;
  if (B < nln) {
    int row = B;
    const float* x; const float* gamma; const float* add; bf16* out; bf16* raw;
    if (row < nln0) { x = x0; gamma = g0; add = a0; out = o0; raw = r0; }
    else { row -= nln0; x = x1; gamma = g1; add = a1; out = o1; raw = r1; }
    const float* xr = x + (size_t)row * 1024;
    float v[4];
    float s = 0.f, ss = 0.f;
#pragma unroll
    for (int i = 0; i < 4; ++i) {
      v[i] = xr[t + 256 * i];
      s += v[i];
      ss += v[i] * v[i];
    }
    if (raw) {
#pragma unroll
      for (int i = 0; i < 4; ++i) raw[(size_t)row * 1024 + t + 256 * i] = f2b(v[i]);
    }
#pragma unroll
    for (int m = 1; m < 64; m <<= 1) {
      s += __shfl_xor(s, m);
      ss += __shfl_xor(ss, m);
    }
    const int wid = t >> 6;
    if ((t & 63) == 0) { red[wid] = s; red[wid + 4] = ss; }
    __syncthreads();
    s = red[0] + red[1] + red[2] + red[3];
    ss = red[4] + red[5] + red[6] + red[7];
    const float mean = s * (1.f / 1024.f);
    const float var = ss * (1.f / 1024.f) - mean * mean;
    const float rs = rsqrtf(var + 1e-5f);
    bf16* outr = out + (size_t)row * 1024;
#pragma unroll
    for (int i = 0; i < 4; ++i) {
      int c = t + 256 * i;
      float y = (v[i] - mean) * rs * gamma[c];
      if (add) y += add[(size_t)row * 1024 + c];
      outr[c] = f2b(y);
    }
    return;
  }
  // ---- wtrans ----
  const int L = B - nln;
  const int y = L / nkx;
  WtPart p;
  int n0;
  if (y < ya) { p = pa; n0 = y * 64; }
  else if (y < yb) { p = pb; n0 = (y - ya) * 64; }
  else if (y < yc) { p = pc; n0 = (y - yb) * 64; }
  else { p = pd; n0 = (y - yc) * 64; }
  const int k0 = (L % nkx) * 64;
  if (k0 >= p.K) return;
  {
    const int kr = t >> 2, np = (t & 3) * 16;
    const float* s = p.src + (size_t)(k0 + kr) * p.N + n0 + np;
    bf16 tmp[16];
#pragma unroll
    for (int i = 0; i < 16; ++i) tmp[i] = f2b(s[i]);
    *(uint4*)&tile[kr][np] = *(uint4*)&tmp[0];
    *(uint4*)&tile[kr][np + 8] = *(uint4*)&tmp[8];
  }
  __syncthreads();
  {
    const int nr = t >> 2, kp = (t & 3) * 16;
    bf16 tmp[16];
#pragma unroll
    for (int i = 0; i < 16; ++i) tmp[i] = tile[kp + i][nr];
    bf16* d = p.dst + (size_t)(n0 + nr) * p.K + k0 + kp;
    *(uint4*)d = *(uint4*)&tmp[0];
    *(uint4*)(d + 8) = *(uint4*)&tmp[8];
  }
}

// ---------------------------------------------------------------------------
// prep_kernel: fused {V transposes} + {bias pre-shuffle}. (l2norm now lives in
// the GEMM epilogue.) [0,1024): vtrans_loc  [1024,1152): vtrans_s
// [1152,3200): bshuf (4 q-rows per block).
// ---------------------------------------------------------------------------
__global__ __launch_bounds__(256) void prep_kernel(
    const bf16* v0src, int v0rs, int v0co, int v0n, bf16* v0dst,
    const bf16* v1src, int v1rs, int v1co, int v1n, bf16* v1dst,
    const float* bias, bf16* bsh) {
  __shared__ bf16 tile[64][72];
  const int t = threadIdx.x;
  int B = blockIdx.x;
  if (B < 1152) {
    const bf16* src; int rstride, coff, nrows; bf16* dst; int n0, h;
    if (B < 1024) {
      src = v0src; rstride = v0rs; coff = v0co; nrows = v0n; dst = v0dst;
      n0 = (B & 63) * 64; h = B >> 6;
    } else {
      const int L = B - 1024;
      src = v1src; rstride = v1rs; coff = v1co; nrows = v1n; dst = v1dst;
      n0 = (L & 7) * 64; h = L >> 3;
    }
    {
      const int nr = t >> 2, dp = (t & 3) * 16;
      const bf16* s = src + (size_t)(n0 + nr) * rstride + coff + h * 64 + dp;
      *(uint4*)&tile[nr][dp] = *(const uint4*)s;
      *(uint4*)&tile[nr][dp + 8] = *(const uint4*)(s + 8);
    }
    __syncthreads();
    {
      const int dr = t >> 2, np = (t & 3) * 16;
      bf16 tmp[16];
#pragma unroll
      for (int i = 0; i < 16; ++i) tmp[i] = tile[np + i][dr];
      bf16* d = dst + (size_t)(h * 64 + dr) * nrows + n0 + np;
      *(uint4*)d = *(uint4*)&tmp[0];
      *(uint4*)(d + 8) = *(uint4*)&tmp[8];
    }
    return;
  }
  B -= 1152;
  // bshuf: bsh[h][q][jt][lr*4+j] = bf16(bias[h][q][jt*64 + j*16 + lr])
  const int h = B >> 7, qq0 = (B & 127) * 4;
  const int jt = t >> 4, lr = t & 15;
#pragma unroll
  for (int qi = 0; qi < 4; ++qi) {
    const int q = qq0 + qi;
    const float* src = bias + ((size_t)h * 512 + q) * 1024 + jt * 64 + lr;
    bf16 b[4];
#pragma unroll
    for (int j = 0; j < 4; ++j) b[j] = f2b(src[j * 16]);
    *(ushort4*)(bsh + (((size_t)h * 512 + q) * 16 + jt) * 64 + lr * 4) = *(ushort4*)b;
  }
}

// ---------------------------------------------------------------------------
// MFMA GEMM v5 (range-dispatched, up to 3 segments per launch).
// C = Acat @ Bt^T; BK=64; global_load_lds staging (bf16 Bt) or strided fp32
// B-source (Bf, cvt during staging); XOR-chunk swizzle both-sides (rule #21);
// chunked XCD swizzle per segment.
// Epilogue: optional per-head l2norm (wave quadrant == one head; reduce =
// 4 regs + 4x shfl_xor over the 16-lane quad group, on the fp32 accumulator),
// optional raw memories side-write (ep&2), optional EMA gate (ep&1).
// ---------------------------------------------------------------------------
__global__ __launch_bounds__(256) void mfma_gemm(
    GemmDesc d0, int b1, GemmDesc d1, int b2, GemmDesc d2,
    const float* b_gate, const float* ema_beta, const float* init_state,
    float* aux) {
  __shared__ bf16 Asb[128][64];
  __shared__ bf16 Bsb[128][64];
  GemmDesc d;
  int local;
  {
    const int B = blockIdx.x;
    if (B < b1) { d = d0; local = B; }
    else if (B < b2) { d = d1; local = B - b1; }
    else { d = d2; local = B - b2; }
  }
  int bxi, byi;
  if (d.cw) {
    const int c = local & 7, r = local >> 3;
    const int nchx = d.nx / d.cw;
    bxi = (c % nchx) * d.cw + r % d.cw;
    byi = (c / nchx) * d.ch + r / d.cw;
  } else {
    bxi = local % d.nx;
    byi = local / d.nx;
  }
  const int bm = byi * 128, bn = bxi * 128;
  const int tid = threadIdx.x;
  const int w = tid >> 6, lane = tid & 63;
  const int wm = (w >> 1) * 64, wn = (w & 1) * 64;
  const int lr = lane & 15, quad = lane >> 4;
  const int srow = (lane >> 3);
  const int sck = ((lane & 7) ^ (lane >> 3)) * 8;

  f32x4 acc[4][4] = {};

  for (int kt = 0; kt < d.K; kt += 64) {
#pragma unroll
    for (int c = 0; c < 4; ++c) {
      const int m = (w * 4 + c) * 8 + srow;
      const int gk = kt + sck;
      const bf16* ap = (d.A2 && gk >= d.K1)
                           ? (d.A2 + (size_t)(bm + m) * d.lda2 + (gk - d.K1))
                           : (d.A + (size_t)(bm + m) * d.lda + gk);
      gload_lds16(ap, &Asb[0][0] + (w * 4 + c) * 512);
    }
    if (d.Bt) {
#pragma unroll
      for (int c = 0; c < 4; ++c) {
        const int n = (w * 4 + c) * 8 + srow;
        gload_lds16(d.Bt + (size_t)(bn + n) * d.K + kt + sck,
                    &Bsb[0][0] + (w * 4 + c) * 512);
      }
    } else {
      // strided fp32 source: Bt[n][k] = Bf[k][n]; same swizzled slot layout
#pragma unroll
      for (int c = 0; c < 4; ++c) {
        const int n = (w * 4 + c) * 8 + srow;
        const float* src = d.Bf + (size_t)(kt + sck) * d.ldbf + bn + n;
        bf16 tmp[8];
#pragma unroll
        for (int e = 0; e < 8; ++e) tmp[e] = f2b(src[(size_t)e * d.ldbf]);
        *(uint4*)(&Bsb[0][0] + (w * 4 + c) * 512 + lane * 8) = *(uint4*)tmp;
      }
    }
    __syncthreads();

#pragma unroll
    for (int dc = 0; dc < 2; ++dc) {
      const int csw = (((dc * 4 + quad) ^ (lr & 7))) * 8;
      bf16x8 af[4], bfr[4];
#pragma unroll
      for (int i = 0; i < 4; ++i)
        af[i] = *(const bf16x8*)&Asb[wm + i * 16 + lr][csw];
#pragma unroll
      for (int j = 0; j < 4; ++j)
        bfr[j] = *(const bf16x8*)&Bsb[wn + j * 16 + lr][csw];
#pragma unroll
      for (int i = 0; i < 4; ++i)
#pragma unroll
        for (int j = 0; j < 4; ++j)
          acc[i][j] = __builtin_amdgcn_mfma_f32_16x16x32_bf16(af[i], bfr[j],
                                                              acc[i][j], 0, 0, 0);
    }
    __syncthreads();
  }

  // ---- epilogue ----
  const int g = (bn + wn) >> 10;  // 1024-col group; uniform per wave
  const int mode = d.nmode[g];
  float sc0 = 1.f, sc1 = 1.f, sc2 = 1.f, sc3 = 1.f;
  if (mode == 1) {
    const float* s1 = d.ns1[g];
    const float* s2 = d.ns2[g];
    float sc[4];
#pragma unroll
    for (int j = 0; j < 4; ++j) {
      const int dd = j * 16 + lr;
      float s = 1.f;
      if (s1) s *= s1[dd];
      if (s2) s *= s2[dd];
      sc[j] = s;
    }
    sc0 = sc[0]; sc1 = sc[1]; sc2 = sc[2]; sc3 = sc[3];
  }
#pragma unroll
  for (int i = 0; i < 4; ++i) {
#pragma unroll
    for (int r = 0; r < 4; ++r) {
      const int row = bm + wm + i * 16 + quad * 4 + r;
      float v0 = acc[i][0][r], v1 = acc[i][1][r], v2 = acc[i][2][r], v3 = acc[i][3][r];
      // memories side-write: RAW k/v rows 3584+, cols [1024,3072)
      if ((d.ep & 2) && row >= 3584 && (g == 1 || g == 2)) {
        const float vr[4] = {v0, v1, v2, v3};
#pragma unroll
        for (int j = 0; j < 4; ++j) {
          const int col = bn + wn + j * 16 + lr;
          const int mm = (col - 1024) >> 10;
          const int hh = (col >> 6) & 15;
          const int dd = col & 63;
          aux[((size_t)((mm * 16 + hh) * 512 + (row - 3584))) * 64 + dd] = vr[j];
        }
      }
      if (mode == 1) {
        float ssq = v0 * v0 + v1 * v1 + v2 * v2 + v3 * v3;
        ssq += __shfl_xor(ssq, 1);
        ssq += __shfl_xor(ssq, 2);
        ssq += __shfl_xor(ssq, 4);
        ssq += __shfl_xor(ssq, 8);
        const float inv = d.nmul[g] / fmaxf(sqrtf(ssq), 1e-12f);
        v0 *= inv * sc0;
        v1 *= inv * sc1;
        v2 *= inv * sc2;
        v3 *= inv * sc3;
      }
      float vv[4] = {v0, v1, v2, v3};
#pragma unroll
      for (int j = 0; j < 4; ++j) {
        const int col = bn + wn + j * 16 + lr;
        float v = vv[j];
        if (d.ep & 1) {
          float z = v + b_gate[col];
          float dd = 1.f / (1.f + __expf(-ema_beta[col]));
          v = dd * z + (1.f - dd) * init_state[(size_t)row * 1024 + col];
        }
        if (d.cf32) ((float*)d.C)[(size_t)row * d.ldc + col] = v;
        else ((bf16*)d.C)[(size_t)row * d.ldc + col] = f2b(v);
      }
    }
  }
}

// ---------------------------------------------------------------------------
// MFMA flash attention v7 (range-dispatched, 4 segments): static-max softmax,
// chunked XCD swizzle, 1-tile-ahead named-register prefetch.
// ---------------------------------------------------------------------------
#define LOAD_KV(JT, K0, K1, V0, V1)                                        \
  {                                                                        \
    const int krow_ = kbase + (JT) + kr;                                   \
    if (krow_ >= 0) {                                                      \
      const bf16* s_ = kp + (size_t)krow_ * k_rstride + h * 64 + kc;       \
      K0 = *(const uint4*)s_;                                              \
      K1 = *(const uint4*)(s_ + 8);                                        \
    } else { K0 = z4; K1 = z4; }                                           \
    const int col_ = kbase + (JT) + kc;                                    \
    if (col_ >= 0) {                                                       \
      const bf16* s_ = vtp + (size_t)(h * 64 + kr) * v_nstride + col_;     \
      V0 = *(const uint4*)s_;                                              \
      V1 = *(const uint4*)(s_ + 8);                                        \
    } else { V0 = z4; V1 = z4; }                                           \
  }

#define STORE_KV(K0, K1, V0, V1)          \
  {                                       \
    *(uint4*)&ksb[kr][kc] = K0;           \
    *(uint4*)&ksb[kr][kc + 8] = K1;       \
    *(uint4*)&vsb[kr][kc] = V0;           \
    *(uint4*)&vsb[kr][kc + 8] = V1;       \
  }

#define LOAD_BIAS(JT, B0, B1, B2, B3)                                      \
  {                                                                        \
    const bf16* bp_ = bshufp + (((size_t)h * 512 + qt * 64 + wq +          \
                                quad * 4) * 16 + ((JT) >> 6)) * 64 + lr * 4; \
    B0 = *(const ushort4*)bp_;                                             \
    B1 = *(const ushort4*)(bp_ + 1024);                                    \
    B2 = *(const ushort4*)(bp_ + 2048);                                    \
    B3 = *(const ushort4*)(bp_ + 3072);                                    \
  }

__global__ __launch_bounds__(256, 4) void attn_mfma(
    AttnDesc d0, int b1, AttnDesc d1, int b2, AttnDesc d2, int b3, AttnDesc d3) {
  __shared__ __align__(16) bf16 ksb[64][72];  // [krow][d]
  __shared__ __align__(16) bf16 vsb[64][72];  // [d][krow]
  __shared__ __align__(16) bf16 psb[64][72];  // [qrow][kcol]
  AttnDesc d;
  int local;
  {
    const int B = blockIdx.x;
    if (B < b1) { d = d0; local = B; }
    else if (B < b2) { d = d1; local = B - b1; }
    else if (B < b3) { d = d2; local = B - b2; }
    else { d = d3; local = B - b3; }
  }
  const bf16* qp = d.qp;
  const int q_rstride = d.q_rstride;
  const bf16* kp = d.kp;
  const int k_rstride = d.k_rstride;
  const bf16* vtp = d.vtp;
  const int v_nstride = d.v_nstride;
  const bf16* bshufp = d.bshuf;
  const int causal = d.causal;

  const int Bp = (local & 7) * (d.nblk >> 3) + (local >> 3);
  const int zb = Bp % d.nzb;
  const int qt = (Bp / d.nzb) % d.nqt;
  const int h = Bp / (d.nzb * d.nqt);
  const int tid = threadIdx.x;
  const int w = tid >> 6, lane = tid & 63;
  const int lr = lane & 15, quad = lane >> 4;
  const int wq = w * 16;
  const int qbase = zb * d.qrows_per_blk + qt * 64;

  bf16x8 qf0, qf1;
  {
    const bf16* qr = qp + (size_t)(qbase + wq + lr) * q_rstride + h * 64 + quad * 8;
    qf0 = *(const bf16x8*)qr;
    qf1 = *(const bf16x8*)(qr + 32);
  }

  float l_i[4] = {0.f, 0.f, 0.f, 0.f};
  f32x4 o_acc[4] = {};

  const int kbase = d.kbase0 + zb * d.krows_per_blk;
  const int ntk = causal ? min(d.nkeys, qt * 64 + 64 + 512) : d.nkeys;
  const int kr = tid >> 2, kc = (tid & 3) * 16;

  const uint4 z4{0, 0, 0, 0};
  uint4 ka0, ka1, va0, va1;
  ushort4 bc0{0,0,0,0}, bc1{0,0,0,0}, bc2{0,0,0,0}, bc3{0,0,0,0};

  LOAD_KV(0, ka0, ka1, va0, va1);
  if (bshufp) LOAD_BIAS(0, bc0, bc1, bc2, bc3);
  STORE_KV(ka0, ka1, va0, va1);

  for (int jt = 0; jt < ntk; jt += 64) {
    __syncthreads();
    const bool pre = jt + 64 < ntk;
    ushort4 bn0{0,0,0,0}, bn1{0,0,0,0}, bn2{0,0,0,0}, bn3{0,0,0,0};
    if (pre) {
      LOAD_KV(jt + 64, ka0, ka1, va0, va1);
      if (bshufp) LOAD_BIAS(jt + 64, bn0, bn1, bn2, bn3);
    }

    // ---- S[16x64] = Q @ K^T ----
    f32x4 s_acc[4] = {};
#pragma unroll
    for (int j = 0; j < 4; ++j) {
      bf16x8 kf = *(const bf16x8*)&ksb[j * 16 + lr][quad * 8];
      s_acc[j] = __builtin_amdgcn_mfma_f32_16x16x32_bf16(qf0, kf, s_acc[j], 0, 0, 0);
    }
#pragma unroll
    for (int j = 0; j < 4; ++j) {
      bf16x8 kf = *(const bf16x8*)&ksb[j * 16 + lr][32 + quad * 8];
      s_acc[j] = __builtin_amdgcn_mfma_f32_16x16x32_bf16(qf1, kf, s_acc[j], 0, 0, 0);
    }

    // ---- bias + causal + static-max softmax (no cross-lane ops) ----
#pragma unroll
    for (int r = 0; r < 4; ++r) {
      const int brow = wq + quad * 4 + r;
      const int qloc = qt * 64 + brow;
      float sv0 = s_acc[0][r], sv1 = s_acc[1][r], sv2 = s_acc[2][r], sv3 = s_acc[3][r];
      if (bshufp) {
        ushort4 bw = (r == 0) ? bc0 : (r == 1) ? bc1 : (r == 2) ? bc2 : bc3;
        bf16 bb[4];
        *(ushort4*)bb = bw;
        sv0 += ldv(bb[0]); sv1 += ldv(bb[1]); sv2 += ldv(bb[2]); sv3 += ldv(bb[3]);
      }
      if (causal) {
        const int lim = qloc + 512;
        if (jt + 0 * 16 + lr > lim) sv0 = -3.0e38f;
        if (jt + 1 * 16 + lr > lim) sv1 = -3.0e38f;
        if (jt + 2 * 16 + lr > lim) sv2 = -3.0e38f;
        if (jt + 3 * 16 + lr > lim) sv3 = -3.0e38f;
      }
      const float p0 = __expf(sv0 - 12.f), p1 = __expf(sv1 - 12.f);
      const float p2 = __expf(sv2 - 12.f), p3 = __expf(sv3 - 12.f);
      l_i[r] += (p0 + p1) + (p2 + p3);
      psb[brow][0 * 16 + lr] = f2b(p0);
      psb[brow][1 * 16 + lr] = f2b(p1);
      psb[brow][2 * 16 + lr] = f2b(p2);
      psb[brow][3 * 16 + lr] = f2b(p3);
    }

    // ---- O[16x64] += P @ V (psb rows wave-private; DS in-order per wave) ----
#pragma unroll
    for (int jc = 0; jc < 2; ++jc) {
      bf16x8 pf = *(const bf16x8*)&psb[wq + lr][jc * 32 + quad * 8];
#pragma unroll
      for (int dt = 0; dt < 4; ++dt) {
        bf16x8 vf = *(const bf16x8*)&vsb[dt * 16 + lr][jc * 32 + quad * 8];
        o_acc[dt] = __builtin_amdgcn_mfma_f32_16x16x32_bf16(pf, vf, o_acc[dt], 0, 0, 0);
      }
    }

    __syncthreads();
    if (pre) {
      STORE_KV(ka0, ka1, va0, va1);
      if (bshufp) { bc0 = bn0; bc1 = bn1; bc2 = bn2; bc3 = bn3; }
    }
  }

  // ---- epilogue: finish the (linear) l reduction across the 16-lane group ----
#pragma unroll
  for (int r = 0; r < 4; ++r) {
#pragma unroll
    for (int mm = 1; mm < 16; mm <<= 1) l_i[r] += __shfl_xor(l_i[r], mm);
    const int qrow = qbase + wq + quad * 4 + r;
    const float invl = 1.f / l_i[r];
    bf16* orow = d.op + (size_t)qrow * d.o_rstride + d.o_coff + (size_t)h * d.o_hstride;
#pragma unroll
    for (int dt = 0; dt < 4; ++dt) orow[dt * 16 + lr] = f2b(o_acc[dt][r] * invl);
  }
}

// ---------------------------------------------------------------------------
extern "C" void kernel_launch(void* const* d_in, const int* in_sizes, int n_in,
                              void* d_out, int out_size, void* d_ws, size_t ws_size,
                              hipStream_t stream) {
  const float* x = (const float*)d_in[0];
  const float* rel_bias = (const float*)d_in[1];
  const float* gamma = (const float*)d_in[2];
  const float* w_qkv = (const float*)d_in[3];
  const float* q_scale = (const float*)d_in[4];
  const float* k_scale = (const float*)d_in[5];
  const float* w_out = (const float*)d_in[6];
  const float* s_gamma = (const float*)d_in[7];
  const float* w_q2s = (const float*)d_in[8];
  const float* w_qfs = (const float*)d_in[9];
  const float* w_sqkv = (const float*)d_in[10];
  const float* init_state = (const float*)d_in[11];
  const float* state_pos = (const float*)d_in[12];
  const float* w_sout = (const float*)d_in[13];
  const float* ts_qs = (const float*)d_in[14];
  const float* ts_ks = (const float*)d_in[15];
  const float* ss_qs = (const float*)d_in[16];
  const float* ss_ks = (const float*)d_in[17];
  const float* fs_qs = (const float*)d_in[18];
  const float* fs_ks = (const float*)d_in[19];
  const float* w_gate = (const float*)d_in[20];
  const float* b_gate = (const float*)d_in[21];
  const float* ema_beta = (const float*)d_in[22];

  // outputs: FP32
  float* out0 = (float*)d_out;         // [4096,1024]
  float* out_mem = out0 + 4194304;     // [2,16,512,64]
  float* out_ns = out0 + 5242880;      // [512,1024]

  // workspace (bf16 intermediates), 64 MiB total
  bf16* xn = (bf16*)d_ws;          // 4096x1024 (reused: vT_loc)
  bf16* proj = xn + 4194304;       // 4096x4096: [q|k|v|q2s] (q/k/q2s normed in epi)
  bf16* aloc = proj + 16777216;    // 4096x1024
  bf16* ats = aloc + 4194304;      // 4096x1024
  bf16* st = ats + 4194304;        // 512x1024 (later reused as vT_s)
  bf16* sqkv = st + 524288;        // 512x3072 (q/k normed in epi, v raw)
  bf16* qfs = sqkv + 1572864;      // 512x1024 (normed in epi)
  bf16* socat = qfs + 524288;      // 512x2048
  bf16* soproj = socat + 1048576;  // 512x1024 (early reuse: ist16)
  bf16* vT_loc = xn;               // [16*64][4096] after proj gemm consumes xn
  bf16* vT_s = st;                 // [16*64][512]  after qfs gemm consumes st
  bf16* ist16 = soproj;            // bf16 copy of init_state (dead before soproj)

  // out0 region as bf16 scratch: early transposed weights, then bshuf
  bf16* out0b = (bf16*)out0;
  bf16* wT_qkv = out0b;                 // 3072x1024 (rows 0-3071 of fused Bt)
  bf16* wT_q2s = wT_qkv + 3145728;      // 1024x1024 (rows 3072-4095, contiguous)
  bf16* wT_sqkv = wT_q2s + 1048576;     // 3072x1024
  bf16* wT_qfs = wT_sqkv + 3145728;     // 1024x1024
  bf16* bshuf = out0b;                  // [16][512][16][64] bf16 (after GEMMs)

  const float* NUL = nullptr;

  // 1. ln(x) + ln(init_state, +raw ist16) + early weight transposes
  {
    WtPart pa{w_qkv, 3072, wT_qkv, 1024};
    WtPart pb{w_q2s, 1024, wT_q2s, 1024};
    WtPart pc{w_sqkv, 3072, wT_sqkv, 1024};
    WtPart pd{w_qfs, 1024, wT_qfs, 1024};
    pre_kernel<<<6656, 256, 0, stream>>>(
        4096, 4608,
        x, gamma, nullptr, xn, nullptr,
        init_state, s_gamma, state_pos, st, ist16,
        16, pa, 48, pb, 64, pc, 112, pd);
  }

  // 2. projections fused (l2norm in epilogue; proj side-writes raw k/v)
  {
    GemmDesc dp{xn, 1024, nullptr, 0, 0, wT_qkv, nullptr, 0, proj, 4096, 1024,
                32, 16, 8, 2, 0, 1024,
                {q_scale, NUL, NUL, ts_qs}, {k_scale, NUL, NUL, ts_ks},
                {8.f, 1.f, 1.f, 8.f}, {1, 1, 0, 1}};
    GemmDesc ds{ist16, 1024, nullptr, 0, 0, wT_sqkv, nullptr, 0, sqkv, 3072, 1024,
                24, 0, 0, 0, 0, 96,
                {ss_qs, NUL, NUL, NUL}, {ss_ks, NUL, NUL, NUL},
                {8.f, 1.f, 1.f, 1.f}, {1, 1, 0, 0}};
    GemmDesc dq{st, 1024, nullptr, 0, 0, wT_qfs, nullptr, 0, qfs, 1024, 1024,
                8, 0, 0, 0, 0, 32,
                {fs_qs, NUL, NUL, NUL}, {fs_ks, NUL, NUL, NUL},
                {8.f, 1.f, 1.f, 1.f}, {1, 0, 0, 0}};
    mfma_gemm<<<1152, 256, 0, stream>>>(dp, 1024, ds, 1120, dq,
                                        b_gate, ema_beta, init_state, out_mem);
  }

  // 3. prep fused: V transposes + bias shuffle (out0 free now)
  prep_kernel<<<3200, 256, 0, stream>>>(
      proj, 4096, 2048, 4096, vT_loc,
      sqkv, 3072, 2048, 512, vT_s,
      rel_bias, bshuf);

  // 4. attentions fused (4 segments; bases %8==0 keep XCD swizzles valid)
  {
    AttnDesc a1{proj, 4096, proj + 1024, 4096, vT_loc, 4096, bshuf,
                1, 1024, 512, -512, 512, 8, 8, 1024, aloc, 1024, 0, 64};
    AttnDesc a2{proj + 3072, 4096, sqkv + 1024, 3072, vT_s, 512, nullptr,
                0, 512, 4096, 0, 0, 64, 1, 1024, ats, 1024, 0, 64};
    AttnDesc a3{sqkv, 3072, sqkv + 1024, 3072, vT_s, 512, nullptr,
                0, 512, 512, 0, 0, 8, 1, 128, socat, 2048, 0, 128};
    AttnDesc a4{qfs, 1024, proj + 1024, 4096, vT_loc, 4096, nullptr,
                0, 512, 512, 3584, 0, 8, 1, 128, socat, 2048, 64, 128};
    attn_mfma<<<2304, 256, 0, stream>>>(a1, 1024, a2, 2048, a3, 2176, a4);
  }

  // 5. out0 = [aloc|ats] @ w_out (fp32, overwrites bshuf) + soproj = socat @ w_sout
  //    (B staged directly from fp32 weights -> no late-wtrans launch)
  {
    GemmDesc da{aloc, 1024, ats, 1024, 1024, nullptr, w_out, 1024, out0, 1024, 2048,
                8, 8, 4, 0, 1, 256,
                {NUL, NUL, NUL, NUL}, {NUL, NUL, NUL, NUL},
                {1.f, 1.f, 1.f, 1.f}, {0, 0, 0, 0}};
    GemmDesc db{socat, 2048, nullptr, 0, 0, nullptr, w_sout, 1024, soproj, 1024, 2048,
                8, 0, 0, 0, 0, 32,
                {NUL, NUL, NUL, NUL}, {NUL, NUL, NUL, NUL},
                {1.f, 1.f, 1.f, 1.f}, {0, 0, 0, 0}};
    mfma_gemm<<<288, 256, 0, stream>>>(da, 256, db, 288, db,
                                       b_gate, ema_beta, init_state, nullptr);
  }

  // 6. new_states = EMA-gate(soproj @ w_gate) (fp32 out)
  {
    GemmDesc dg{soproj, 1024, nullptr, 0, 0, nullptr, w_gate, 1024, out_ns, 1024, 1024,
                8, 0, 0, 1, 1, 32,
                {NUL, NUL, NUL, NUL}, {NUL, NUL, NUL, NUL},
                {1.f, 1.f, 1.f, 1.f}, {0, 0, 0, 0}};
    mfma_gemm<<<32, 256, 0, stream>>>(dg, 32, dg, 32, dg,
                                      b_gate, ema_beta, init_state, nullptr);
  }
}